// Round 9
// baseline (515.494 us; speedup 1.0000x reference)
//
#include <hip/hip_runtime.h>

// Problem constants (match reference)
constexpr int NGPH = 128;            // graphs per batch
constexpr int NPG  = 1024;           // nodes per graph
constexpr int NN   = NGPH * NPG;     // 131072 nodes
constexpr int HD   = 128;            // feature width (FIN == H == 128)
constexpr int EPG  = 16384;          // edges per graph (E // B), contiguous per graph
constexpr int KS1 = 820, KS2 = 656, KS3 = 525;

typedef _Float16 half4v __attribute__((ext_vector_type(4)));
typedef _Float16 half8v __attribute__((ext_vector_type(8)));
typedef float f32x4 __attribute__((ext_vector_type(4)));

// K-loop barrier: drain LDS ops, hardware barrier, then a compiler fence on
// BOTH sides so no memory op is hoisted above the barrier (llvm.amdgcn.s.barrier
// has no memory-fence semantics of its own; __syncthreads = fence+barrier+
// vmcnt(0) drain, which would kill the global prefetch pipeline).
#define LBAR() do { \
  asm volatile("s_waitcnt lgkmcnt(0)" ::: "memory"); \
  __builtin_amdgcn_s_barrier(); \
  __builtin_amdgcn_sched_barrier(0); \
  asm volatile("" ::: "memory"); \
} while (0)

// ---------------------------------------------------------------------------
// Build per-graph incoming-CSR (counting sort by dst). One block per graph.
// Output overwrites the graph's own src-half of edge_index:
//   [g*64KB, +32KB) : src_sorted ushort[16384];  [+32KB, +2KB) : rs ushort[1024]
__global__ __launch_bounds__(512) void csr_build(int* __restrict__ ei) {
  __shared__ unsigned int ed[EPG];   // packed src | dst<<10  (64 KB)
  __shared__ int cnt[NPG];
  __shared__ int scn[NPG];
  __shared__ int off[NPG];
  int g = blockIdx.x, t = threadIdx.x;
  const int* srcg = ei + (size_t)g * EPG;
  const int* dstg = ei + (size_t)NGPH * EPG + (size_t)g * EPG;
  for (int i = t; i < EPG; i += 512) {
    unsigned int s = (unsigned int)(srcg[i] - (g << 10));
    unsigned int d = (unsigned int)(dstg[i] - (g << 10));
    ed[i] = s | (d << 10);
  }
  for (int i = t; i < NPG; i += 512) cnt[i] = 0;
  __syncthreads();
  for (int i = t; i < EPG; i += 512) atomicAdd(&cnt[ed[i] >> 10], 1);
  __syncthreads();
  int* a = cnt; int* b = scn;
  for (int d = 1; d < NPG; d <<= 1) {
    for (int i = t; i < NPG; i += 512) b[i] = a[i] + (i >= d ? a[i - d] : 0);
    __syncthreads();
    int* tmp = a; a = b; b = tmp;
  }
  unsigned short* ssort = (unsigned short*)(ei + (size_t)g * EPG);
  unsigned short* rsout = ssort + EPG;
  for (int r = t; r < NPG; r += 512) {
    int ex = r ? a[r - 1] : 0;
    rsout[r] = (unsigned short)ex;
    off[r] = ex;
  }
  __syncthreads();
  for (int i = t; i < EPG; i += 512) {
    unsigned int e = ed[i];
    int pos = atomicAdd(&off[e >> 10], 1);
    ssort[pos] = (unsigned short)(e & 1023u);
  }
}

// ---------------------------------------------------------------------------
// One launch: fp32 -> hi/lo fp16 split of all three [Wl | Wr] into planes
// (dst-half of edge_index, dead after csr_build), plus zero the per-graph
// done-counters used by the fused gemm+topk.
// Per layer: WH[n*256+k] hi, WH[32768 + n*256+k] lo.
__global__ __launch_bounds__(256) void wsplit3(const float* __restrict__ Wl1,
                                               const float* __restrict__ Wr1,
                                               const float* __restrict__ Wl2,
                                               const float* __restrict__ Wr2,
                                               const float* __restrict__ Wl3,
                                               const float* __restrict__ Wr3,
                                               _Float16* __restrict__ WH,
                                               int* __restrict__ dcnt) {
  int b = blockIdx.x;
  int layer = b >> 7;
  int i = (b & 127) * 256 + threadIdx.x;    // 0..32767 = 128 n x 256 k
  const float* Wl = (layer == 0) ? Wl1 : (layer == 1) ? Wl2 : Wl3;
  const float* Wr = (layer == 0) ? Wr1 : (layer == 1) ? Wr2 : Wr3;
  _Float16* W = WH + layer * 65536;
  int n = i >> 8, k = i & 255;
  float v = (k < 128) ? Wl[n * HD + k] : Wr[n * HD + (k - 128)];
  _Float16 h = (_Float16)v;
  W[i] = h;
  W[32768 + i] = (_Float16)(v - (float)h);
  if (b == 0 && threadIdx.x < 3 * NGPH) dcnt[threadIdx.x] = 0;
}

// ---------------------------------------------------------------------------
// Mean aggregation via CSR gather — proven R4 body (shfl broadcast, unroll 4,
// float4, XCD swizzle, dead-dst skip), templated:
//   GATED=false (layer 1): gate identically 1 -> no gate reads, no gv shfls,
//   no skip, deg = end-start. Bit-identical math (v*1.0 == v).
// Output: fp32 mean split hi/lo fp16 planes: Sp[row*256+k]=hi, +128=lo.
template <bool GATED>
__global__ __launch_bounds__(256) void agg2_kernel(const float* __restrict__ X,
                                                   const int* __restrict__ ei,
                                                   const float* __restrict__ gate,
                                                   _Float16* __restrict__ Sp) {
  int t = threadIdx.x;
  int xcd = blockIdx.x & 7, q = blockIdx.x >> 3;
  int g = ((q >> 7) << 3) + xcd;
  int r = (q & 127) * 8 + (t >> 5);
  int lane = t & 31;
  int gbase = g << 10;

  if (GATED && gate[gbase + r] == 0.f) return;   // dead dst; no barriers -> safe

  const unsigned short* ss  = (const unsigned short*)(ei + (size_t)g * EPG);
  const unsigned short* rsg = ss + EPG;
  int start = rsg[r];
  int end   = (r < 1023) ? (int)rsg[r + 1] : EPG;
  const float4* X4 = (const float4*)X;
  size_t gb4 = (size_t)gbase * 32;
  float4 acc = make_float4(0.f, 0.f, 0.f, 0.f);
  float degf = 0.f;
  for (int base = start; base < end; base += 32) {
    int ec = end - base; if (ec > 32) ec = 32;
    int sl = 0; float gv = 0.f;
    if (lane < ec) {
      sl = ss[base + lane];
      if (GATED) gv = gate[gbase + sl];
    }
    if (GATED) degf += (gv != 0.f) ? 1.f : 0.f;
    int e = 0;
    for (; e + 4 <= ec; e += 4) {
      int s0 = __shfl(sl, e, 32),     s1 = __shfl(sl, e + 1, 32);
      int s2 = __shfl(sl, e + 2, 32), s3 = __shfl(sl, e + 3, 32);
      float g0 = GATED ? __shfl(gv, e, 32)     : 1.0f;
      float g1 = GATED ? __shfl(gv, e + 1, 32) : 1.0f;
      float g2 = GATED ? __shfl(gv, e + 2, 32) : 1.0f;
      float g3 = GATED ? __shfl(gv, e + 3, 32) : 1.0f;
      float4 v0 = X4[gb4 + (size_t)s0 * 32 + lane];
      float4 v1 = X4[gb4 + (size_t)s1 * 32 + lane];
      float4 v2 = X4[gb4 + (size_t)s2 * 32 + lane];
      float4 v3 = X4[gb4 + (size_t)s3 * 32 + lane];
      acc.x += v0.x * g0 + v1.x * g1 + v2.x * g2 + v3.x * g3;
      acc.y += v0.y * g0 + v1.y * g1 + v2.y * g2 + v3.y * g3;
      acc.z += v0.z * g0 + v1.z * g1 + v2.z * g2 + v3.z * g3;
      acc.w += v0.w * g0 + v1.w * g1 + v2.w * g2 + v3.w * g3;
    }
    for (; e < ec; ++e) {
      int s0 = __shfl(sl, e, 32);
      float g0 = GATED ? __shfl(gv, e, 32) : 1.0f;
      float4 v0 = X4[gb4 + (size_t)s0 * 32 + lane];
      acc.x += v0.x * g0; acc.y += v0.y * g0;
      acc.z += v0.z * g0; acc.w += v0.w * g0;
    }
  }
  if (GATED) {
#pragma unroll
    for (int m = 1; m <= 16; m <<= 1) degf += __shfl_xor(degf, m, 32);
  } else {
    degf = (float)(end - start);
  }
  float inv = 1.0f / fmaxf(degf, 1.0f);
  acc.x *= inv; acc.y *= inv; acc.z *= inv; acc.w *= inv;
  half4v h, l;
  h.x = (_Float16)acc.x; h.y = (_Float16)acc.y;
  h.z = (_Float16)acc.z; h.w = (_Float16)acc.w;
  l.x = (_Float16)(acc.x - (float)h.x); l.y = (_Float16)(acc.y - (float)h.y);
  l.z = (_Float16)(acc.z - (float)h.z); l.w = (_Float16)(acc.w - (float)h.w);
  size_t rowb = (size_t)(gbase + r) * 256;
  *(half4v*)&Sp[rowb + lane * 4]       = h;
  *(half4v*)&Sp[rowb + 128 + lane * 4] = l;
}

// ---------------------------------------------------------------------------
// Hout = relu( S @ Wl^T + (X*gate) @ Wr^T + bias ) via fp16-split MFMA
// (R4 pipelined body), fused score = relu(H).wp (DETERMINISTIC: per-wave
// partials in fixed-order sum, no float atomics), and fused per-graph TOP-K
// (last-block-done; proven radix select inline). K-loop barriers are
// lgkmcnt-only + raw s_barrier (+ post-barrier compiler fence) so the
// software-pipelined global prefetches stay in flight across barriers
// (a full __syncthreads drains vmcnt(0) and re-exposes HBM/L2 latency every
// step — the measured MfmaUtil-13% stall).
constexpr int LDA = 40;   // fp16 elements per LDS row (32 + 8 pad)
template <bool GATED>
__global__ __launch_bounds__(256) void gemm_mfma(const _Float16* Sp,
                                                 const float* __restrict__ X,
                                                 const _Float16* __restrict__ WH,
                                                 const float* __restrict__ bb,
                                                 const float* __restrict__ wp,
                                                 float* gate,
                                                 float* Hout,
                                                 float* score,
                                                 int* __restrict__ dcnt,
                                                 int kk) {
  __shared__ _Float16 Ah[128 * LDA];
  __shared__ _Float16 Al[128 * LDA];
  __shared__ float gsh[128];
  __shared__ float sc_p[128][2];   // deterministic score partials [row][wn]
  __shared__ int s_done;
  __shared__ float shv;
  __shared__ unsigned s_pfx;
  __shared__ int s_need;
  int t = threadIdx.x;
  int r0 = blockIdx.x * 128;
  int lane = t & 63, wid = t >> 6;
  int wm = wid & 1, wn = wid >> 1;
  int quad = lane >> 4, mr = lane & 15;

  // S-plane chunk addressing: 512 chunks of 16 B per plane per step;
  // chunk c: row = c>>2, kq = (c&3)*8 halves. Two chunks per thread.
  int c0 = t, c1 = t + 256;
  int row0 = c0 >> 2, kq0 = (c0 & 3) * 8;
  int row1 = c1 >> 2, kq1 = (c1 & 3) * 8;
  const char* spb = (const char*)(Sp + (size_t)r0 * 256);

  // prologue: issue S loads for ks=0 before anything else
  int4 ph0 = *(const int4*)(spb + row0 * 512 + kq0 * 2);
  int4 ph1 = *(const int4*)(spb + row1 * 512 + kq1 * 2);
  int4 pl0 = *(const int4*)(spb + row0 * 512 + 256 + kq0 * 2);
  int4 pl1 = *(const int4*)(spb + row1 * 512 + 256 + kq1 * 2);
  float4 px[4];

  if (GATED && t < 128) gsh[t] = gate[r0 + t];
  LBAR();   // gsh visible to all waves; no vmcnt drain (prefetch stays live)

  f32x4 acc[4][4];
#pragma unroll
  for (int i = 0; i < 4; ++i)
#pragma unroll
    for (int j = 0; j < 4; ++j) acc[i][j] = (f32x4){0.f, 0.f, 0.f, 0.f};

  half8v af[4], alf[4], bf[4], blf[4];

  // ---- S-half: ks = 0..127, pre-split copy staging, pipelined
  for (int ks = 0; ks < 128; ks += 32) {
    *(int4*)&Ah[row0 * LDA + kq0] = ph0;
    *(int4*)&Ah[row1 * LDA + kq1] = ph1;
    *(int4*)&Al[row0 * LDA + kq0] = pl0;
    *(int4*)&Al[row1 * LDA + kq1] = pl1;
    if (ks < 96) {
      int ko = (ks + 32) * 2;
      ph0 = *(const int4*)(spb + row0 * 512 + ko + kq0 * 2);
      ph1 = *(const int4*)(spb + row1 * 512 + ko + kq1 * 2);
      pl0 = *(const int4*)(spb + row0 * 512 + 256 + ko + kq0 * 2);
      pl1 = *(const int4*)(spb + row1 * 512 + 256 + ko + kq1 * 2);
    } else {
      const float* Asrc = X + (size_t)r0 * HD;   // X step ks=128
#pragma unroll
      for (int i = 0; i < 4; ++i) {
        int f = t + i * 256;
        int row = f >> 3;
        int kq = (f & 7) * 4;
        px[i] = *(const float4*)&Asrc[(size_t)row * HD + kq];
      }
    }
    LBAR();
#pragma unroll
    for (int i = 0; i < 4; ++i) {
      int rowA = (wm * 64 + i * 16 + mr) * LDA + quad * 8;
      af[i]  = *(const half8v*)&Ah[rowA];
      alf[i] = *(const half8v*)&Al[rowA];
    }
#pragma unroll
    for (int j = 0; j < 4; ++j) {
      const _Float16* bp = WH + (wn * 64 + j * 16 + mr) * 256 + ks + quad * 8;
      bf[j]  = *(const half8v*)bp;
      blf[j] = *(const half8v*)(bp + 32768);
    }
#pragma unroll
    for (int i = 0; i < 4; ++i)
#pragma unroll
      for (int j = 0; j < 4; ++j) {
        acc[i][j] = __builtin_amdgcn_mfma_f32_16x16x32_f16(af[i],  bf[j],  acc[i][j], 0, 0, 0);
        acc[i][j] = __builtin_amdgcn_mfma_f32_16x16x32_f16(af[i],  blf[j], acc[i][j], 0, 0, 0);
        acc[i][j] = __builtin_amdgcn_mfma_f32_16x16x32_f16(alf[i], bf[j],  acc[i][j], 0, 0, 0);
      }
    LBAR();
  }

  // ---- X-half: ks = 128..255, fp32 convert staging (gated), pipelined
  for (int ks = 128; ks < 256; ks += 32) {
#pragma unroll
    for (int i = 0; i < 4; ++i) {
      int f = t + i * 256;
      int row = f >> 3;
      int kq = (f & 7) * 4;
      float4 v = px[i];
      if (GATED) {
        float gv = gsh[row];
        v.x *= gv; v.y *= gv; v.z *= gv; v.w *= gv;
      }
      half4v h, l;
      h.x = (_Float16)v.x; h.y = (_Float16)v.y; h.z = (_Float16)v.z; h.w = (_Float16)v.w;
      l.x = (_Float16)(v.x - (float)h.x); l.y = (_Float16)(v.y - (float)h.y);
      l.z = (_Float16)(v.z - (float)h.z); l.w = (_Float16)(v.w - (float)h.w);
      *(half4v*)&Ah[row * LDA + kq] = h;
      *(half4v*)&Al[row * LDA + kq] = l;
    }
    if (ks < 224) {
      const float* Asrc = X + (size_t)r0 * HD + (ks - 96);   // next step's k
#pragma unroll
      for (int i = 0; i < 4; ++i) {
        int f = t + i * 256;
        int row = f >> 3;
        int kq = (f & 7) * 4;
        px[i] = *(const float4*)&Asrc[(size_t)row * HD + kq];
      }
    }
    LBAR();
#pragma unroll
    for (int i = 0; i < 4; ++i) {
      int rowA = (wm * 64 + i * 16 + mr) * LDA + quad * 8;
      af[i]  = *(const half8v*)&Ah[rowA];
      alf[i] = *(const half8v*)&Al[rowA];
    }
#pragma unroll
    for (int j = 0; j < 4; ++j) {
      const _Float16* bp = WH + (wn * 64 + j * 16 + mr) * 256 + ks + quad * 8;
      bf[j]  = *(const half8v*)bp;
      blf[j] = *(const half8v*)(bp + 32768);
    }
#pragma unroll
    for (int i = 0; i < 4; ++i)
#pragma unroll
      for (int j = 0; j < 4; ++j) {
        acc[i][j] = __builtin_amdgcn_mfma_f32_16x16x32_f16(af[i],  bf[j],  acc[i][j], 0, 0, 0);
        acc[i][j] = __builtin_amdgcn_mfma_f32_16x16x32_f16(af[i],  blf[j], acc[i][j], 0, 0, 0);
        acc[i][j] = __builtin_amdgcn_mfma_f32_16x16x32_f16(alf[i], bf[j],  acc[i][j], 0, 0, 0);
      }
    LBAR();
  }

  // ---- epilogue: bias + relu (+dead-row zero) + H store + fused score
  float p[4][4];
#pragma unroll
  for (int i = 0; i < 4; ++i)
#pragma unroll
    for (int r = 0; r < 4; ++r) p[i][r] = 0.f;
#pragma unroll
  for (int j = 0; j < 4; ++j) {
    int col = wn * 64 + j * 16 + mr;
    float bias = bb[col];
    float wv = wp[col];
#pragma unroll
    for (int i = 0; i < 4; ++i) {
      int rowl = wm * 64 + i * 16 + quad * 4;
#pragma unroll
      for (int r = 0; r < 4; ++r) {
        bool alive = !GATED || (gsh[rowl + r] != 0.f);
        float ho = alive ? fmaxf(acc[i][j][r] + bias, 0.f) : 0.f;
        Hout[(size_t)(r0 + rowl + r) * HD + col] = ho;
        p[i][r] += ho * wv;
      }
    }
  }
  // deterministic per-wave partials: lane mr==0 of each 16-lane row-group
#pragma unroll
  for (int i = 0; i < 4; ++i)
#pragma unroll
    for (int r = 0; r < 4; ++r) {
#pragma unroll
      for (int m = 1; m <= 8; m <<= 1) p[i][r] += __shfl_xor(p[i][r], m, 16);
      if (mr == 0) sc_p[wm * 64 + i * 16 + quad * 4 + r][wn] = p[i][r];
    }
  __syncthreads();
  // publish scores at agent scope (fixed-order sum -> deterministic)
  if (t < 128)
    __hip_atomic_store(&score[r0 + t], sc_p[t][0] + sc_p[t][1],
                       __ATOMIC_RELAXED, __HIP_MEMORY_SCOPE_AGENT);
  __syncthreads();   // full drain -> our stores visible before counter bump
  int gph = r0 >> 10;
  if (t == 0)
    s_done = __hip_atomic_fetch_add(&dcnt[gph], 1, __ATOMIC_RELAXED,
                                    __HIP_MEMORY_SCOPE_AGENT);
  __syncthreads();
  if (s_done != 7) return;

  // ---- fused per-graph TOP-K (radix select, proven logic), last block only
  int gb = gph << 10;
  float* sc = (float*)Ah;                         // 4 KB  (Ah = 10.25 KB)
  unsigned* key = (unsigned*)((char*)Ah + 4096);  // 4 KB
  int* hist = (int*)Al;                           // 1 KB
  if (t == 0) {
    float ss = 0.f;
    for (int i = 0; i < HD; ++i) ss += wp[i] * wp[i];
    shv = 1.0f / (sqrtf(ss) + 1e-16f);
    s_pfx = 0u; s_need = kk;
  }
  __syncthreads();
  float inv = shv;
#pragma unroll
  for (int q = 0; q < 4; ++q) {
    int n = t + q * 256;
    float s = __hip_atomic_load(&score[gb + n], __ATOMIC_RELAXED,
                                __HIP_MEMORY_SCOPE_AGENT) * inv;
    sc[n] = s;
    unsigned u = __float_as_uint(s);
    u = (u & 0x80000000u) ? ~u : (u | 0x80000000u);
    key[n] = (!GATED || gate[gb + n] != 0.f) ? u : 0u;
  }
  for (int shift = 24; shift >= 0; shift -= 8) {
    hist[t] = 0;
    __syncthreads();
    unsigned pfx = s_pfx;
    unsigned mask = (shift == 24) ? 0u : (0xFFFFFFFFu << (shift + 8));
#pragma unroll
    for (int q = 0; q < 4; ++q) {
      unsigned u = key[t + q * 256];
      if ((u & mask) == (pfx & mask))
        atomicAdd(&hist[(u >> shift) & 255], 1);
    }
    __syncthreads();
    if (t < 64) {   // wave 0: suffix-scan 256 bins, pick threshold bin
      int c0 = hist[t * 4 + 0], c1 = hist[t * 4 + 1];
      int c2 = hist[t * 4 + 2], c3 = hist[t * 4 + 3];
      int s3 = c3, s2 = c2 + s3, s1 = c1 + s2, s0 = c0 + s1;
      int tot = s0;
      int suf = tot;
#pragma unroll
      for (int off = 1; off < 64; off <<= 1) {
        int v = __shfl_down(suf, off, 64);
        if (t + off < 64) suf += v;
      }
      int above = suf - tot;               // sum over lanes > t
      int need = s_need;
      int best = -1;                       // largest bin with cum-from-top >= need
      if      (above + s3 >= need) best = t * 4 + 3;
      else if (above + s2 >= need) best = t * 4 + 2;
      else if (above + s1 >= need) best = t * 4 + 1;
      else if (above + s0 >= need) best = t * 4 + 0;
#pragma unroll
      for (int off = 1; off < 64; off <<= 1) {
        int v = __shfl_xor(best, off, 64);
        best = best > v ? best : v;
      }
      if ((best >> 2) == t) {              // owner lane updates state
        int j = best & 3;
        int sj = (j == 0) ? s0 : (j == 1) ? s1 : (j == 2) ? s2 : s3;
        int cj = (j == 0) ? c0 : (j == 1) ? c1 : (j == 2) ? c2 : c3;
        s_need = need - (above + sj - cj); // subtract strictly-above count
        s_pfx  = pfx | ((unsigned)best << shift);
      }
    }
    __syncthreads();
  }
  unsigned thr = s_pfx;                    // exact key of kth-largest
#pragma unroll
  for (int q = 0; q < 4; ++q) {
    int n = t + q * 256;
    bool sel = (key[n] != 0u) && (key[n] >= thr);
    gate[gb + n] = sel ? tanhf(sc[n]) : 0.f;
  }
}

// ---------------------------------------------------------------------------
// global mean pool of gate-weighted rows (divisor exactly K3), MLP, log_softmax.
// 512 threads: 16 row-chunks x 32 float4 cols, coalesced, dead rows skipped.
__global__ __launch_bounds__(512) void final_kernel(const float* __restrict__ X,
                                                    const float* __restrict__ gate,
                                                    const float* __restrict__ Wf1,
                                                    const float* __restrict__ bf1,
                                                    const float* __restrict__ Wf2,
                                                    const float* __restrict__ bf2,
                                                    float* __restrict__ out) {
  __shared__ float gs[NPG];
  __shared__ float4 part[16][32];
  __shared__ float pl[HD];
  __shared__ float h1[64];
  __shared__ float lg[10];
  __shared__ float red[2];
  int g = blockIdx.x, t = threadIdx.x;
  for (int i = t; i < NPG; i += 512) gs[i] = gate[(g << 10) + i];
  __syncthreads();
  int slot = t & 31, chunk = t >> 5;
  const float4* X4 = (const float4*)X + (size_t)(g << 10) * 32;
  float4 acc = make_float4(0.f, 0.f, 0.f, 0.f);
  for (int rr = 0; rr < 64; ++rr) {
    int row = chunk * 64 + rr;
    float w = gs[row];
    if (w != 0.f) {
      float4 v = X4[(size_t)row * 32 + slot];
      acc.x += v.x * w; acc.y += v.y * w; acc.z += v.z * w; acc.w += v.w * w;
    }
  }
  part[chunk][slot] = acc;
  __syncthreads();
  if (t < 32) {
    float4 s = part[0][t];
#pragma unroll
    for (int c = 1; c < 16; ++c) {
      float4 p = part[c][t];
      s.x += p.x; s.y += p.y; s.z += p.z; s.w += p.w;
    }
    float k = 1.0f / (float)KS3;
    pl[t * 4 + 0] = s.x * k; pl[t * 4 + 1] = s.y * k;
    pl[t * 4 + 2] = s.z * k; pl[t * 4 + 3] = s.w * k;
  }
  __syncthreads();
  if (t < 64) {
    float h = bf1[t];
    for (int f = 0; f < HD; ++f) h += pl[f] * Wf1[t * HD + f];
    h1[t] = fmaxf(h, 0.f);
  }
  __syncthreads();
  if (t < 10) {
    float z = bf2[t];
    for (int j = 0; j < 64; ++j) z += h1[j] * Wf2[t * 64 + j];
    lg[t] = z;
  }
  __syncthreads();
  if (t == 0) {
    float m = lg[0];
    for (int c = 1; c < 10; ++c) m = fmaxf(m, lg[c]);
    float ssum = 0.f;
    for (int c = 0; c < 10; ++c) ssum += expf(lg[c] - m);
    red[0] = m; red[1] = logf(ssum);
  }
  __syncthreads();
  if (t < 10) out[g * 10 + t] = lg[t] - red[0] - red[1];
}

// ---------------------------------------------------------------------------
extern "C" void kernel_launch(void* const* d_in, const int* in_sizes, int n_in,
                              void* d_out, int out_size, void* d_ws, size_t ws_size,
                              hipStream_t stream) {
  const float* x  = (const float*)d_in[0];
  int* ei         = (int*)d_in[1];          // src half -> CSR; dst half -> W planes + counters
  const float* Wl[3]  = {(const float*)d_in[2], (const float*)d_in[6],  (const float*)d_in[10]};
  const float* blv[3] = {(const float*)d_in[3], (const float*)d_in[7],  (const float*)d_in[11]};
  const float* Wr[3]  = {(const float*)d_in[4], (const float*)d_in[8],  (const float*)d_in[12]};
  const float* wp[3]  = {(const float*)d_in[5], (const float*)d_in[9],  (const float*)d_in[13]};
  const float* Wf1 = (const float*)d_in[14];
  const float* bf1 = (const float*)d_in[15];
  const float* Wf2 = (const float*)d_in[16];
  const float* bf2 = (const float*)d_in[17];
  float* out = (float*)d_out;

  // workspace: bufA (64MB) | bufB (64MB) | gate (512KB) | score (512KB)
  // Each 64MB buffer holds either H (fp32 [row][128]) or S planes
  // (fp16 [row][hi 128 | lo 128]) — same 512 B/row footprint, in-place.
  float* bufA  = (float*)d_ws;
  float* bufB  = bufA + (size_t)NN * HD;
  float* gate  = bufB + (size_t)NN * HD;
  float* score = gate + NN;
  _Float16* spA = (_Float16*)bufA;
  _Float16* spB = (_Float16*)bufB;

  // W hi/lo planes + per-graph done-counters live in the dst-half of
  // edge_index (dead after csr_build)
  _Float16* wpl = (_Float16*)(ei + (size_t)NGPH * EPG);
  int* dcnt = (int*)(wpl + 3 * 65536);      // 3 layers x 128 graphs

  csr_build<<<NGPH, 512, 0, stream>>>(ei);  // must precede wsplit3 (reads dst half)
  wsplit3<<<384, 256, 0, stream>>>(Wl[0], Wr[0], Wl[1], Wr[1], Wl[2], Wr[2], wpl, dcnt);

  // L1 (ungated): x -> S planes (bufA) -> gemm+topk in-place bufA
  agg2_kernel<false><<<NN / 8, 256, 0, stream>>>(x, ei, gate, spA);
  gemm_mfma<false><<<NN / 128, 256, 0, stream>>>(spA, x, wpl, blv[0], wp[0], gate, bufA, score, dcnt, KS1);
  // L2
  agg2_kernel<true><<<NN / 8, 256, 0, stream>>>(bufA, ei, gate, spB);
  gemm_mfma<true><<<NN / 128, 256, 0, stream>>>(spB, bufA, wpl + 65536, blv[1], wp[1], gate, bufB, score, dcnt + NGPH, KS2);
  // L3
  agg2_kernel<true><<<NN / 8, 256, 0, stream>>>(bufB, ei, gate, spA);
  gemm_mfma<true><<<NN / 128, 256, 0, stream>>>(spA, bufB, wpl + 131072, blv[2], wp[2], gate, bufA, score, dcnt + 2 * NGPH, KS3);

  final_kernel<<<NGPH, 512, 0, stream>>>(bufA, gate, Wf1, bf1, Wf2, bf2, out);
}

// Round 10
// 474.967 us; speedup vs baseline: 1.0853x; 1.0853x over previous
//
#include <hip/hip_runtime.h>

// Problem constants (match reference)
constexpr int NGPH = 128;            // graphs per batch
constexpr int NPG  = 1024;           // nodes per graph
constexpr int NN   = NGPH * NPG;     // 131072 nodes
constexpr int HD   = 128;            // feature width (FIN == H == 128)
constexpr int EPG  = 16384;          // edges per graph (E // B), contiguous per graph
constexpr int KS1 = 820, KS2 = 656, KS3 = 525;

typedef _Float16 half4v __attribute__((ext_vector_type(4)));
typedef _Float16 half8v __attribute__((ext_vector_type(8)));
typedef float f32x4 __attribute__((ext_vector_type(4)));

// ---------------------------------------------------------------------------
// Build per-graph incoming-CSR (counting sort by dst). One block per graph.
// Output overwrites the graph's own src-half of edge_index:
//   [g*64KB, +32KB) : src_sorted ushort[16384];  [+32KB, +2KB) : rs ushort[1024]
__global__ __launch_bounds__(512) void csr_build(int* __restrict__ ei) {
  __shared__ unsigned int ed[EPG];   // packed src | dst<<10  (64 KB)
  __shared__ int cnt[NPG];
  __shared__ int scn[NPG];
  __shared__ int off[NPG];
  int g = blockIdx.x, t = threadIdx.x;
  const int* srcg = ei + (size_t)g * EPG;
  const int* dstg = ei + (size_t)NGPH * EPG + (size_t)g * EPG;
  for (int i = t; i < EPG; i += 512) {
    unsigned int s = (unsigned int)(srcg[i] - (g << 10));
    unsigned int d = (unsigned int)(dstg[i] - (g << 10));
    ed[i] = s | (d << 10);
  }
  for (int i = t; i < NPG; i += 512) cnt[i] = 0;
  __syncthreads();
  for (int i = t; i < EPG; i += 512) atomicAdd(&cnt[ed[i] >> 10], 1);
  __syncthreads();
  int* a = cnt; int* b = scn;
  for (int d = 1; d < NPG; d <<= 1) {
    for (int i = t; i < NPG; i += 512) b[i] = a[i] + (i >= d ? a[i - d] : 0);
    __syncthreads();
    int* tmp = a; a = b; b = tmp;
  }
  unsigned short* ssort = (unsigned short*)(ei + (size_t)g * EPG);
  unsigned short* rsout = ssort + EPG;
  for (int r = t; r < NPG; r += 512) {
    int ex = r ? a[r - 1] : 0;
    rsout[r] = (unsigned short)ex;
    off[r] = ex;
  }
  __syncthreads();
  for (int i = t; i < EPG; i += 512) {
    unsigned int e = ed[i];
    int pos = atomicAdd(&off[e >> 10], 1);
    ssort[pos] = (unsigned short)(e & 1023u);
  }
}

// ---------------------------------------------------------------------------
// One launch: fp32 -> hi/lo fp16 split of all three [Wl | Wr] into planes
// (dst-half of edge_index, dead after csr_build), plus zero the per-graph
// done-counters used by the fused gemm+topk.
// Per layer: WH[n*256+k] hi, WH[32768 + n*256+k] lo.
__global__ __launch_bounds__(256) void wsplit3(const float* __restrict__ Wl1,
                                               const float* __restrict__ Wr1,
                                               const float* __restrict__ Wl2,
                                               const float* __restrict__ Wr2,
                                               const float* __restrict__ Wl3,
                                               const float* __restrict__ Wr3,
                                               _Float16* __restrict__ WH,
                                               int* __restrict__ dcnt) {
  int b = blockIdx.x;
  int layer = b >> 7;
  int i = (b & 127) * 256 + threadIdx.x;    // 0..32767 = 128 n x 256 k
  const float* Wl = (layer == 0) ? Wl1 : (layer == 1) ? Wl2 : Wl3;
  const float* Wr = (layer == 0) ? Wr1 : (layer == 1) ? Wr2 : Wr3;
  _Float16* W = WH + layer * 65536;
  int n = i >> 8, k = i & 255;
  float v = (k < 128) ? Wl[n * HD + k] : Wr[n * HD + (k - 128)];
  _Float16 h = (_Float16)v;
  W[i] = h;
  W[32768 + i] = (_Float16)(v - (float)h);
  if (b == 0 && threadIdx.x < 3 * NGPH) dcnt[threadIdx.x] = 0;
}

// ---------------------------------------------------------------------------
// Mean aggregation via CSR gather — proven R4 body (shfl broadcast, unroll 4,
// float4, XCD swizzle, dead-dst skip), templated:
//   GATED=false (layer 1): gate identically 1 -> no gate reads, no gv shfls,
//   no skip, deg = end-start. Bit-identical math (v*1.0 == v).
// Output: fp32 mean split hi/lo fp16 planes: Sp[row*256+k]=hi, +128=lo.
template <bool GATED>
__global__ __launch_bounds__(256) void agg2_kernel(const float* __restrict__ X,
                                                   const int* __restrict__ ei,
                                                   const float* __restrict__ gate,
                                                   _Float16* __restrict__ Sp) {
  int t = threadIdx.x;
  int xcd = blockIdx.x & 7, q = blockIdx.x >> 3;
  int g = ((q >> 7) << 3) + xcd;
  int r = (q & 127) * 8 + (t >> 5);
  int lane = t & 31;
  int gbase = g << 10;

  if (GATED && gate[gbase + r] == 0.f) return;   // dead dst; no barriers -> safe

  const unsigned short* ss  = (const unsigned short*)(ei + (size_t)g * EPG);
  const unsigned short* rsg = ss + EPG;
  int start = rsg[r];
  int end   = (r < 1023) ? (int)rsg[r + 1] : EPG;
  const float4* X4 = (const float4*)X;
  size_t gb4 = (size_t)gbase * 32;
  float4 acc = make_float4(0.f, 0.f, 0.f, 0.f);
  float degf = 0.f;
  for (int base = start; base < end; base += 32) {
    int ec = end - base; if (ec > 32) ec = 32;
    int sl = 0; float gv = 0.f;
    if (lane < ec) {
      sl = ss[base + lane];
      if (GATED) gv = gate[gbase + sl];
    }
    if (GATED) degf += (gv != 0.f) ? 1.f : 0.f;
    int e = 0;
    for (; e + 4 <= ec; e += 4) {
      int s0 = __shfl(sl, e, 32),     s1 = __shfl(sl, e + 1, 32);
      int s2 = __shfl(sl, e + 2, 32), s3 = __shfl(sl, e + 3, 32);
      float g0 = GATED ? __shfl(gv, e, 32)     : 1.0f;
      float g1 = GATED ? __shfl(gv, e + 1, 32) : 1.0f;
      float g2 = GATED ? __shfl(gv, e + 2, 32) : 1.0f;
      float g3 = GATED ? __shfl(gv, e + 3, 32) : 1.0f;
      float4 v0 = X4[gb4 + (size_t)s0 * 32 + lane];
      float4 v1 = X4[gb4 + (size_t)s1 * 32 + lane];
      float4 v2 = X4[gb4 + (size_t)s2 * 32 + lane];
      float4 v3 = X4[gb4 + (size_t)s3 * 32 + lane];
      acc.x += v0.x * g0 + v1.x * g1 + v2.x * g2 + v3.x * g3;
      acc.y += v0.y * g0 + v1.y * g1 + v2.y * g2 + v3.y * g3;
      acc.z += v0.z * g0 + v1.z * g1 + v2.z * g2 + v3.z * g3;
      acc.w += v0.w * g0 + v1.w * g1 + v2.w * g2 + v3.w * g3;
    }
    for (; e < ec; ++e) {
      int s0 = __shfl(sl, e, 32);
      float g0 = GATED ? __shfl(gv, e, 32) : 1.0f;
      float4 v0 = X4[gb4 + (size_t)s0 * 32 + lane];
      acc.x += v0.x * g0; acc.y += v0.y * g0;
      acc.z += v0.z * g0; acc.w += v0.w * g0;
    }
  }
  if (GATED) {
#pragma unroll
    for (int m = 1; m <= 16; m <<= 1) degf += __shfl_xor(degf, m, 32);
  } else {
    degf = (float)(end - start);
  }
  float inv = 1.0f / fmaxf(degf, 1.0f);
  acc.x *= inv; acc.y *= inv; acc.z *= inv; acc.w *= inv;
  half4v h, l;
  h.x = (_Float16)acc.x; h.y = (_Float16)acc.y;
  h.z = (_Float16)acc.z; h.w = (_Float16)acc.w;
  l.x = (_Float16)(acc.x - (float)h.x); l.y = (_Float16)(acc.y - (float)h.y);
  l.z = (_Float16)(acc.z - (float)h.z); l.w = (_Float16)(acc.w - (float)h.w);
  size_t rowb = (size_t)(gbase + r) * 256;
  *(half4v*)&Sp[rowb + lane * 4]       = h;
  *(half4v*)&Sp[rowb + 128 + lane * 4] = l;
}

// ---------------------------------------------------------------------------
// Hout = relu( S @ Wl^T + (X*gate) @ Wr^T + bias ) via fp16-split MFMA,
// fused deterministic score = relu(H).wp, fused per-graph TOP-K
// (last-block-done radix select). NEW this round: B (the W planes) is staged
// through LDS as a pure int4 copy, software-pipelined one K-step ahead like
// S/X — MFMA fragments now come entirely from ds_read_b128 (~12cy) instead
// of 512B-strided global loads (~200cy L2) sitting in the MFMA feed path,
// and per-block B traffic halves (no per-wave duplication).
// Barriers are plain __syncthreads (LBAR experiments regressed/crashed).
constexpr int LDA = 40;   // fp16 elements per LDS row (32 + 8 pad)
template <bool GATED>
__global__ __launch_bounds__(256) void gemm_mfma(const _Float16* Sp,
                                                 const float* __restrict__ X,
                                                 const _Float16* __restrict__ WH,
                                                 const float* __restrict__ bb,
                                                 const float* __restrict__ wp,
                                                 float* gate,
                                                 float* Hout,
                                                 float* score,
                                                 int* __restrict__ dcnt,
                                                 int kk) {
  __shared__ _Float16 Ah[128 * LDA];
  __shared__ _Float16 Al[128 * LDA];
  __shared__ _Float16 Bh[128 * LDA];
  __shared__ _Float16 Bl[128 * LDA];
  __shared__ float gsh[128];
  __shared__ float sc_p[128][2];   // deterministic score partials [row][wn]
  __shared__ int s_done;
  __shared__ float shv;
  __shared__ unsigned s_pfx;
  __shared__ int s_need;
  int t = threadIdx.x;
  int r0 = blockIdx.x * 128;
  int lane = t & 63, wid = t >> 6;
  int wm = wid & 1, wn = wid >> 1;
  int quad = lane >> 4, mr = lane & 15;

  // chunk addressing (shared by S and B staging): 512 16B-chunks per plane
  // per step; chunk c: row/n = c>>2, kq = (c&3)*8 halves. 2 chunks/thread.
  int c0 = t, c1 = t + 256;
  int row0 = c0 >> 2, kq0 = (c0 & 3) * 8;
  int row1 = c1 >> 2, kq1 = (c1 & 3) * 8;
  const char* spb = (const char*)(Sp + (size_t)r0 * 256);

  // prologue: issue S and B loads for ks=0 before anything else
  int4 ph0 = *(const int4*)(spb + row0 * 512 + kq0 * 2);
  int4 ph1 = *(const int4*)(spb + row1 * 512 + kq1 * 2);
  int4 pl0 = *(const int4*)(spb + row0 * 512 + 256 + kq0 * 2);
  int4 pl1 = *(const int4*)(spb + row1 * 512 + 256 + kq1 * 2);
  int4 pb0 = *(const int4*)(WH + row0 * 256 + kq0);
  int4 pb1 = *(const int4*)(WH + row1 * 256 + kq1);
  int4 pbl0 = *(const int4*)(WH + 32768 + row0 * 256 + kq0);
  int4 pbl1 = *(const int4*)(WH + 32768 + row1 * 256 + kq1);
  float4 px[4];

  if (t < 128) { if (GATED) gsh[t] = gate[r0 + t]; }
  // visibility of gsh: first in-loop __syncthreads precedes any gsh use

  f32x4 acc[4][4];
#pragma unroll
  for (int i = 0; i < 4; ++i)
#pragma unroll
    for (int j = 0; j < 4; ++j) acc[i][j] = (f32x4){0.f, 0.f, 0.f, 0.f};

  half8v af[4], alf[4], bf[4], blf[4];

  // ---- S-half: ks = 0..127, pre-split copy staging (A and B), pipelined
  for (int ks = 0; ks < 128; ks += 32) {
    *(int4*)&Ah[row0 * LDA + kq0] = ph0;
    *(int4*)&Ah[row1 * LDA + kq1] = ph1;
    *(int4*)&Al[row0 * LDA + kq0] = pl0;
    *(int4*)&Al[row1 * LDA + kq1] = pl1;
    *(int4*)&Bh[row0 * LDA + kq0] = pb0;
    *(int4*)&Bh[row1 * LDA + kq1] = pb1;
    *(int4*)&Bl[row0 * LDA + kq0] = pbl0;
    *(int4*)&Bl[row1 * LDA + kq1] = pbl1;
    {
      int kn = ks + 32;
      pb0 = *(const int4*)(WH + row0 * 256 + kn + kq0);
      pb1 = *(const int4*)(WH + row1 * 256 + kn + kq1);
      pbl0 = *(const int4*)(WH + 32768 + row0 * 256 + kn + kq0);
      pbl1 = *(const int4*)(WH + 32768 + row1 * 256 + kn + kq1);
    }
    if (ks < 96) {
      int ko = (ks + 32) * 2;
      ph0 = *(const int4*)(spb + row0 * 512 + ko + kq0 * 2);
      ph1 = *(const int4*)(spb + row1 * 512 + ko + kq1 * 2);
      pl0 = *(const int4*)(spb + row0 * 512 + 256 + ko + kq0 * 2);
      pl1 = *(const int4*)(spb + row1 * 512 + 256 + ko + kq1 * 2);
    } else {
      const float* Asrc = X + (size_t)r0 * HD;   // X step ks=128
#pragma unroll
      for (int i = 0; i < 4; ++i) {
        int f = t + i * 256;
        int row = f >> 3;
        int kq = (f & 7) * 4;
        px[i] = *(const float4*)&Asrc[(size_t)row * HD + kq];
      }
    }
    __syncthreads();
#pragma unroll
    for (int i = 0; i < 4; ++i) {
      int rowA = (wm * 64 + i * 16 + mr) * LDA + quad * 8;
      af[i]  = *(const half8v*)&Ah[rowA];
      alf[i] = *(const half8v*)&Al[rowA];
    }
#pragma unroll
    for (int j = 0; j < 4; ++j) {
      int rowB = (wn * 64 + j * 16 + mr) * LDA + quad * 8;
      bf[j]  = *(const half8v*)&Bh[rowB];
      blf[j] = *(const half8v*)&Bl[rowB];
    }
#pragma unroll
    for (int i = 0; i < 4; ++i)
#pragma unroll
      for (int j = 0; j < 4; ++j) {
        acc[i][j] = __builtin_amdgcn_mfma_f32_16x16x32_f16(af[i],  bf[j],  acc[i][j], 0, 0, 0);
        acc[i][j] = __builtin_amdgcn_mfma_f32_16x16x32_f16(af[i],  blf[j], acc[i][j], 0, 0, 0);
        acc[i][j] = __builtin_amdgcn_mfma_f32_16x16x32_f16(alf[i], bf[j],  acc[i][j], 0, 0, 0);
      }
    __syncthreads();
  }

  // ---- X-half: ks = 128..255, fp32 convert staging (gated) + B copy, pipelined
  for (int ks = 128; ks < 256; ks += 32) {
#pragma unroll
    for (int i = 0; i < 4; ++i) {
      int f = t + i * 256;
      int row = f >> 3;
      int kq = (f & 7) * 4;
      float4 v = px[i];
      if (GATED) {
        float gv = gsh[row];
        v.x *= gv; v.y *= gv; v.z *= gv; v.w *= gv;
      }
      half4v h, l;
      h.x = (_Float16)v.x; h.y = (_Float16)v.y; h.z = (_Float16)v.z; h.w = (_Float16)v.w;
      l.x = (_Float16)(v.x - (float)h.x); l.y = (_Float16)(v.y - (float)h.y);
      l.z = (_Float16)(v.z - (float)h.z); l.w = (_Float16)(v.w - (float)h.w);
      *(half4v*)&Ah[row * LDA + kq] = h;
      *(half4v*)&Al[row * LDA + kq] = l;
    }
    *(int4*)&Bh[row0 * LDA + kq0] = pb0;
    *(int4*)&Bh[row1 * LDA + kq1] = pb1;
    *(int4*)&Bl[row0 * LDA + kq0] = pbl0;
    *(int4*)&Bl[row1 * LDA + kq1] = pbl1;
    if (ks < 224) {
      int kn = ks + 32;
      pb0 = *(const int4*)(WH + row0 * 256 + kn + kq0);
      pb1 = *(const int4*)(WH + row1 * 256 + kn + kq1);
      pbl0 = *(const int4*)(WH + 32768 + row0 * 256 + kn + kq0);
      pbl1 = *(const int4*)(WH + 32768 + row1 * 256 + kn + kq1);
      const float* Asrc = X + (size_t)r0 * HD + (ks - 96);   // next step's k
#pragma unroll
      for (int i = 0; i < 4; ++i) {
        int f = t + i * 256;
        int row = f >> 3;
        int kq = (f & 7) * 4;
        px[i] = *(const float4*)&Asrc[(size_t)row * HD + kq];
      }
    }
    __syncthreads();
#pragma unroll
    for (int i = 0; i < 4; ++i) {
      int rowA = (wm * 64 + i * 16 + mr) * LDA + quad * 8;
      af[i]  = *(const half8v*)&Ah[rowA];
      alf[i] = *(const half8v*)&Al[rowA];
    }
#pragma unroll
    for (int j = 0; j < 4; ++j) {
      int rowB = (wn * 64 + j * 16 + mr) * LDA + quad * 8;
      bf[j]  = *(const half8v*)&Bh[rowB];
      blf[j] = *(const half8v*)&Bl[rowB];
    }
#pragma unroll
    for (int i = 0; i < 4; ++i)
#pragma unroll
      for (int j = 0; j < 4; ++j) {
        acc[i][j] = __builtin_amdgcn_mfma_f32_16x16x32_f16(af[i],  bf[j],  acc[i][j], 0, 0, 0);
        acc[i][j] = __builtin_amdgcn_mfma_f32_16x16x32_f16(af[i],  blf[j], acc[i][j], 0, 0, 0);
        acc[i][j] = __builtin_amdgcn_mfma_f32_16x16x32_f16(alf[i], bf[j],  acc[i][j], 0, 0, 0);
      }
    __syncthreads();
  }

  // ---- epilogue: bias + relu (+dead-row zero) + H store + fused score
  float p[4][4];
#pragma unroll
  for (int i = 0; i < 4; ++i)
#pragma unroll
    for (int r = 0; r < 4; ++r) p[i][r] = 0.f;
#pragma unroll
  for (int j = 0; j < 4; ++j) {
    int col = wn * 64 + j * 16 + mr;
    float bias = bb[col];
    float wv = wp[col];
#pragma unroll
    for (int i = 0; i < 4; ++i) {
      int rowl = wm * 64 + i * 16 + quad * 4;
#pragma unroll
      for (int r = 0; r < 4; ++r) {
        bool alive = !GATED || (gsh[rowl + r] != 0.f);
        float ho = alive ? fmaxf(acc[i][j][r] + bias, 0.f) : 0.f;
        Hout[(size_t)(r0 + rowl + r) * HD + col] = ho;
        p[i][r] += ho * wv;
      }
    }
  }
  // deterministic per-wave partials: lane mr==0 of each 16-lane row-group
#pragma unroll
  for (int i = 0; i < 4; ++i)
#pragma unroll
    for (int r = 0; r < 4; ++r) {
#pragma unroll
      for (int m = 1; m <= 8; m <<= 1) p[i][r] += __shfl_xor(p[i][r], m, 16);
      if (mr == 0) sc_p[wm * 64 + i * 16 + quad * 4 + r][wn] = p[i][r];
    }
  __syncthreads();
  // publish scores at agent scope (fixed-order sum -> deterministic)
  if (t < 128)
    __hip_atomic_store(&score[r0 + t], sc_p[t][0] + sc_p[t][1],
                       __ATOMIC_RELAXED, __HIP_MEMORY_SCOPE_AGENT);
  __syncthreads();   // full drain -> our stores visible before counter bump
  int gph = r0 >> 10;
  if (t == 0)
    s_done = __hip_atomic_fetch_add(&dcnt[gph], 1, __ATOMIC_RELAXED,
                                    __HIP_MEMORY_SCOPE_AGENT);
  __syncthreads();
  if (s_done != 7) return;

  // ---- fused per-graph TOP-K (radix select, proven logic), last block only
  int gb = gph << 10;
  float* sc = (float*)Ah;                         // 4 KB  (Ah = 10.25 KB)
  unsigned* key = (unsigned*)((char*)Ah + 4096);  // 4 KB
  int* hist = (int*)Al;                           // 1 KB
  if (t == 0) {
    float ss = 0.f;
    for (int i = 0; i < HD; ++i) ss += wp[i] * wp[i];
    shv = 1.0f / (sqrtf(ss) + 1e-16f);
    s_pfx = 0u; s_need = kk;
  }
  __syncthreads();
  float inv = shv;
#pragma unroll
  for (int q = 0; q < 4; ++q) {
    int n = t + q * 256;
    float s = __hip_atomic_load(&score[gb + n], __ATOMIC_RELAXED,
                                __HIP_MEMORY_SCOPE_AGENT) * inv;
    sc[n] = s;
    unsigned u = __float_as_uint(s);
    u = (u & 0x80000000u) ? ~u : (u | 0x80000000u);
    key[n] = (!GATED || gate[gb + n] != 0.f) ? u : 0u;
  }
  for (int shift = 24; shift >= 0; shift -= 8) {
    hist[t] = 0;
    __syncthreads();
    unsigned pfx = s_pfx;
    unsigned mask = (shift == 24) ? 0u : (0xFFFFFFFFu << (shift + 8));
#pragma unroll
    for (int q = 0; q < 4; ++q) {
      unsigned u = key[t + q * 256];
      if ((u & mask) == (pfx & mask))
        atomicAdd(&hist[(u >> shift) & 255], 1);
    }
    __syncthreads();
    if (t < 64) {   // wave 0: suffix-scan 256 bins, pick threshold bin
      int c0h = hist[t * 4 + 0], c1h = hist[t * 4 + 1];
      int c2h = hist[t * 4 + 2], c3h = hist[t * 4 + 3];
      int s3 = c3h, s2 = c2h + s3, s1 = c1h + s2, s0 = c0h + s1;
      int tot = s0;
      int suf = tot;
#pragma unroll
      for (int off = 1; off < 64; off <<= 1) {
        int v = __shfl_down(suf, off, 64);
        if (t + off < 64) suf += v;
      }
      int above = suf - tot;               // sum over lanes > t
      int need = s_need;
      int best = -1;                       // largest bin with cum-from-top >= need
      if      (above + s3 >= need) best = t * 4 + 3;
      else if (above + s2 >= need) best = t * 4 + 2;
      else if (above + s1 >= need) best = t * 4 + 1;
      else if (above + s0 >= need) best = t * 4 + 0;
#pragma unroll
      for (int off = 1; off < 64; off <<= 1) {
        int v = __shfl_xor(best, off, 64);
        best = best > v ? best : v;
      }
      if ((best >> 2) == t) {              // owner lane updates state
        int j = best & 3;
        int sj = (j == 0) ? s0 : (j == 1) ? s1 : (j == 2) ? s2 : s3;
        int cj = (j == 0) ? c0h : (j == 1) ? c1h : (j == 2) ? c2h : c3h;
        s_need = need - (above + sj - cj); // subtract strictly-above count
        s_pfx  = pfx | ((unsigned)best << shift);
      }
    }
    __syncthreads();
  }
  unsigned thr = s_pfx;                    // exact key of kth-largest
#pragma unroll
  for (int q = 0; q < 4; ++q) {
    int n = t + q * 256;
    bool sel = (key[n] != 0u) && (key[n] >= thr);
    gate[gb + n] = sel ? tanhf(sc[n]) : 0.f;
  }
}

// ---------------------------------------------------------------------------
// global mean pool of gate-weighted rows (divisor exactly K3), MLP, log_softmax.
// 512 threads: 16 row-chunks x 32 float4 cols, coalesced, dead rows skipped.
__global__ __launch_bounds__(512) void final_kernel(const float* __restrict__ X,
                                                    const float* __restrict__ gate,
                                                    const float* __restrict__ Wf1,
                                                    const float* __restrict__ bf1,
                                                    const float* __restrict__ Wf2,
                                                    const float* __restrict__ bf2,
                                                    float* __restrict__ out) {
  __shared__ float gs[NPG];
  __shared__ float4 part[16][32];
  __shared__ float pl[HD];
  __shared__ float h1[64];
  __shared__ float lg[10];
  __shared__ float red[2];
  int g = blockIdx.x, t = threadIdx.x;
  for (int i = t; i < NPG; i += 512) gs[i] = gate[(g << 10) + i];
  __syncthreads();
  int slot = t & 31, chunk = t >> 5;
  const float4* X4 = (const float4*)X + (size_t)(g << 10) * 32;
  float4 acc = make_float4(0.f, 0.f, 0.f, 0.f);
  for (int rr = 0; rr < 64; ++rr) {
    int row = chunk * 64 + rr;
    float w = gs[row];
    if (w != 0.f) {
      float4 v = X4[(size_t)row * 32 + slot];
      acc.x += v.x * w; acc.y += v.y * w; acc.z += v.z * w; acc.w += v.w * w;
    }
  }
  part[chunk][slot] = acc;
  __syncthreads();
  if (t < 32) {
    float4 s = part[0][t];
#pragma unroll
    for (int c = 1; c < 16; ++c) {
      float4 p = part[c][t];
      s.x += p.x; s.y += p.y; s.z += p.z; s.w += p.w;
    }
    float k = 1.0f / (float)KS3;
    pl[t * 4 + 0] = s.x * k; pl[t * 4 + 1] = s.y * k;
    pl[t * 4 + 2] = s.z * k; pl[t * 4 + 3] = s.w * k;
  }
  __syncthreads();
  if (t < 64) {
    float h = bf1[t];
    for (int f = 0; f < HD; ++f) h += pl[f] * Wf1[t * HD + f];
    h1[t] = fmaxf(h, 0.f);
  }
  __syncthreads();
  if (t < 10) {
    float z = bf2[t];
    for (int j = 0; j < 64; ++j) z += h1[j] * Wf2[t * 64 + j];
    lg[t] = z;
  }
  __syncthreads();
  if (t == 0) {
    float m = lg[0];
    for (int c = 1; c < 10; ++c) m = fmaxf(m, lg[c]);
    float ssum = 0.f;
    for (int c = 0; c < 10; ++c) ssum += expf(lg[c] - m);
    red[0] = m; red[1] = logf(ssum);
  }
  __syncthreads();
  if (t < 10) out[g * 10 + t] = lg[t] - red[0] - red[1];
}

// ---------------------------------------------------------------------------
extern "C" void kernel_launch(void* const* d_in, const int* in_sizes, int n_in,
                              void* d_out, int out_size, void* d_ws, size_t ws_size,
                              hipStream_t stream) {
  const float* x  = (const float*)d_in[0];
  int* ei         = (int*)d_in[1];          // src half -> CSR; dst half -> W planes + counters
  const float* Wl[3]  = {(const float*)d_in[2], (const float*)d_in[6],  (const float*)d_in[10]};
  const float* blv[3] = {(const float*)d_in[3], (const float*)d_in[7],  (const float*)d_in[11]};
  const float* Wr[3]  = {(const float*)d_in[4], (const float*)d_in[8],  (const float*)d_in[12]};
  const float* wp[3]  = {(const float*)d_in[5], (const float*)d_in[9],  (const float*)d_in[13]};
  const float* Wf1 = (const float*)d_in[14];
  const float* bf1 = (const float*)d_in[15];
  const float* Wf2 = (const float*)d_in[16];
  const float* bf2 = (const float*)d_in[17];
  float* out = (float*)d_out;

  // workspace: bufA (64MB) | bufB (64MB) | gate (512KB) | score (512KB)
  // Each 64MB buffer holds either H (fp32 [row][128]) or S planes
  // (fp16 [row][hi 128 | lo 128]) — same 512 B/row footprint, in-place.
  float* bufA  = (float*)d_ws;
  float* bufB  = bufA + (size_t)NN * HD;
  float* gate  = bufB + (size_t)NN * HD;
  float* score = gate + NN;
  _Float16* spA = (_Float16*)bufA;
  _Float16* spB = (_Float16*)bufB;

  // W hi/lo planes + per-graph done-counters live in the dst-half of
  // edge_index (dead after csr_build)
  _Float16* wpl = (_Float16*)(ei + (size_t)NGPH * EPG);
  int* dcnt = (int*)(wpl + 3 * 65536);      // 3 layers x 128 graphs

  csr_build<<<NGPH, 512, 0, stream>>>(ei);  // must precede wsplit3 (reads dst half)
  wsplit3<<<384, 256, 0, stream>>>(Wl[0], Wr[0], Wl[1], Wr[1], Wl[2], Wr[2], wpl, dcnt);

  // L1 (ungated): x -> S planes (bufA) -> gemm+topk in-place bufA
  agg2_kernel<false><<<NN / 8, 256, 0, stream>>>(x, ei, gate, spA);
  gemm_mfma<false><<<NN / 128, 256, 0, stream>>>(spA, x, wpl, blv[0], wp[0], gate, bufA, score, dcnt, KS1);
  // L2
  agg2_kernel<true><<<NN / 8, 256, 0, stream>>>(bufA, ei, gate, spB);
  gemm_mfma<true><<<NN / 128, 256, 0, stream>>>(spB, bufA, wpl + 65536, blv[1], wp[1], gate, bufB, score, dcnt + NGPH, KS2);
  // L3
  agg2_kernel<true><<<NN / 8, 256, 0, stream>>>(bufB, ei, gate, spA);
  gemm_mfma<true><<<NN / 128, 256, 0, stream>>>(spA, bufB, wpl + 131072, blv[2], wp[2], gate, bufA, score, dcnt + 2 * NGPH, KS3);

  final_kernel<<<NGPH, 512, 0, stream>>>(bufA, gate, Wf1, bf1, Wf2, bf2, out);
}